// Round 2
// baseline (6301.150 us; speedup 1.0000x reference)
//
#include <hip/hip_runtime.h>
#include <hip/hip_fp16.h>

// 2-layer LSTM (T=1024, B=1024, H=100) + FC, fused in one persistent kernel.
// 64 blocks x 512 threads; block owns 16 batch rows, loops 1025 epochs.
// Waves 0-2: layer-0 hh GEMM (MFMA 16x16x32 f16, K padded 128, x+bias folded
// into K-slots 100-103). Waves 3-7: layer-1 concat GEMM (K=224: W_ih1 at k<100,
// W_hh1 at k in [112,212), bias at k=212), lagged one step (software pipeline).
// All weights resident as register B-fragments. h-state in swizzled LDS (f16),
// cell state f32 in registers, gates f32 in LDS.

#define T_SEQ 1024
#define NG 400

typedef __attribute__((ext_vector_type(8))) _Float16 half8;
typedef __attribute__((ext_vector_type(4))) float f32x4;

__device__ __forceinline__ unsigned short f2h(float f) {
  _Float16 h = (_Float16)f;
  return *reinterpret_cast<unsigned short*>(&h);
}

__device__ __forceinline__ float sigmoid_f(float x) {
  // 1/(1+2^(-x*log2e)); exp2f/ division lower to v_exp_f32 + rcp sequence.
  return 1.0f / (1.0f + exp2f(-1.4426950408889634f * x));
}
__device__ __forceinline__ float tanh_f(float x) {
  return 1.0f - 2.0f / (1.0f + exp2f(2.8853900817779268f * x));
}

// Swizzled f16 store into hcat: row b (0..15), slot s (0..255).
// byte = b*512 + ((2s) ^ ((b&7)<<4))  -- matches the b128 A-fragment reads.
__device__ __forceinline__ void hset(unsigned short* hcat, int b, int s, unsigned short v) {
  int byte = b * 512 + ((s * 2) ^ ((b & 7) << 4));
  *reinterpret_cast<unsigned short*>(reinterpret_cast<char*>(hcat) + byte) = v;
}

// ---- weight fragment loaders (init only) ----
template<int NT_, int TB>
__device__ __forceinline__ void load_w0(half8 (&wf)[36], const float* Whh0, const float* Wih0,
                                        const float* bih0, const float* bhh0, int lane) {
  const int r = lane & 15, hi = lane >> 4;
  #pragma unroll
  for (int t = 0; t < NT_; ++t) {
    const int g = (TB + t) * 16 + r;
    #pragma unroll
    for (int ks = 0; ks < 4; ++ks) {
      half8 v;
      #pragma unroll
      for (int j = 0; j < 8; ++j) {
        const int k = ks * 32 + hi * 8 + j;
        float val = 0.f;
        if (k < 100) val = Whh0[g * 100 + k];
        else if (k < 103) val = Wih0[g * 3 + (k - 100)];
        else if (k == 103) val = bih0[g] + bhh0[g];
        v[j] = (_Float16)val;
      }
      wf[t * 4 + ks] = v;
    }
  }
}

template<int TB>
__device__ __forceinline__ void load_w1(half8 (&wf)[36], const float* Wih1, const float* Whh1,
                                        const float* bih1, const float* bhh1, int lane) {
  const int r = lane & 15, hi = lane >> 4;
  #pragma unroll
  for (int t = 0; t < 5; ++t) {
    const int g = (TB + t) * 16 + r;
    #pragma unroll
    for (int ks = 0; ks < 7; ++ks) {
      half8 v;
      #pragma unroll
      for (int j = 0; j < 8; ++j) {
        const int k = ks * 32 + hi * 8 + j;
        float val = 0.f;
        if (k < 100) val = Wih1[g * 100 + k];
        else if (k >= 112 && k < 212) val = Whh1[g * 100 + (k - 112)];
        else if (k == 212) val = bih1[g] + bhh1[g];
        v[j] = (_Float16)val;
      }
      wf[t * 7 + ks] = v;
    }
  }
}

// ---- per-epoch GEMMs ----
// A-frag: lane holds A[r=lane&15][k = (lane>>4)*8 + j]; B-frag: B[k][c=lane&15].
// D: col=lane&15 (gate), row=(lane>>4)*4+reg (batch)  [m89-verified layout].
template<int NT_, int TB>
__device__ __forceinline__ void gemm0_run(const half8 (&wf)[36], const unsigned short* hcat,
                                          float* gates, int lane) {
  const int r = lane & 15, hi = lane >> 4;
  const int swz = (r & 7) << 4;
  const char* hb = reinterpret_cast<const char*>(hcat);
  half8 a[4];
  #pragma unroll
  for (int ks = 0; ks < 4; ++ks)
    a[ks] = *reinterpret_cast<const half8*>(hb + r * 512 + ((ks * 64 + hi * 16) ^ swz));
  f32x4 acc[NT_];
  #pragma unroll
  for (int t = 0; t < NT_; ++t) acc[t] = f32x4{0.f, 0.f, 0.f, 0.f};
  #pragma unroll
  for (int ks = 0; ks < 4; ++ks) {
    #pragma unroll
    for (int t = 0; t < NT_; ++t)
      acc[t] = __builtin_amdgcn_mfma_f32_16x16x32_f16(a[ks], wf[t * 4 + ks], acc[t], 0, 0, 0);
  }
  #pragma unroll
  for (int t = 0; t < NT_; ++t) {
    const int g = (TB + t) * 16 + r;
    const int q = (g >= 300) ? 3 : (g >= 200) ? 2 : (g >= 100) ? 1 : 0;
    const int u = g - q * 100;
    #pragma unroll
    for (int q2 = 0; q2 < 4; ++q2)
      gates[((hi * 4 + q2) * 100 + u) * 4 + q] = acc[t][q2];
  }
}

template<int TB>
__device__ __forceinline__ void gemm1_run(const half8 (&wf)[36], const unsigned short* hcat,
                                          float* gates, int lane) {
  const int r = lane & 15, hi = lane >> 4;
  const int swz = (r & 7) << 4;
  const char* hb = reinterpret_cast<const char*>(hcat);
  half8 a[7];
  #pragma unroll
  for (int ks = 0; ks < 7; ++ks)
    a[ks] = *reinterpret_cast<const half8*>(hb + r * 512 + ((ks * 64 + hi * 16) ^ swz));
  f32x4 acc[5];
  #pragma unroll
  for (int t = 0; t < 5; ++t) acc[t] = f32x4{0.f, 0.f, 0.f, 0.f};
  #pragma unroll
  for (int ks = 0; ks < 7; ++ks) {
    #pragma unroll
    for (int t = 0; t < 5; ++t)
      acc[t] = __builtin_amdgcn_mfma_f32_16x16x32_f16(a[ks], wf[t * 7 + ks], acc[t], 0, 0, 0);
  }
  #pragma unroll
  for (int t = 0; t < 5; ++t) {
    const int g = (TB + t) * 16 + r;
    const int q = (g >= 300) ? 3 : (g >= 200) ? 2 : (g >= 100) ? 1 : 0;
    const int u = g - q * 100;
    #pragma unroll
    for (int q2 = 0; q2 < 4; ++q2)
      gates[((hi * 4 + q2) * 100 + u) * 4 + q] = acc[t][q2];
  }
}

__global__ __launch_bounds__(512, 2)
void lstm2_kernel(const float* __restrict__ x,
                  const float* __restrict__ Wih0, const float* __restrict__ Whh0,
                  const float* __restrict__ bih0, const float* __restrict__ bhh0,
                  const float* __restrict__ Wih1, const float* __restrict__ Whh1,
                  const float* __restrict__ bih1, const float* __restrict__ bhh1,
                  const float* __restrict__ fcw, const float* __restrict__ fcb,
                  float* __restrict__ out) {
  // hcat slots: [0,100)=h0, 100-102=x(t), 103=1.0 (bias for GEMM0),
  //             [112,212)=h1, 212=1.0 (bias for GEMM1). Rows swizzled.
  __shared__ unsigned short hcat[16 * 256];        // 8 KB
  __shared__ float gates0[16 * 100 * 4];           // 25.6 KB, [b][u][q] q=i,f,g,o
  __shared__ float gates1[16 * 100 * 4];           // 25.6 KB

  const int tid  = threadIdx.x;
  const int lane = tid & 63;
  const int wid  = tid >> 6;
  const int b0   = blockIdx.x << 4;

  half8 wf[36];   // role-unioned register weight fragments (144 VGPR)
  #pragma unroll
  for (int i = 0; i < 36; ++i) wf[i] = half8{0,0,0,0,0,0,0,0};

  if (wid == 0)      load_w0<9, 0 >(wf, Whh0, Wih0, bih0, bhh0, lane);
  else if (wid == 1) load_w0<8, 9 >(wf, Whh0, Wih0, bih0, bhh0, lane);
  else if (wid == 2) load_w0<8, 17>(wf, Whh0, Wih0, bih0, bhh0, lane);
  else if (wid == 3) load_w1<0 >(wf, Wih1, Whh1, bih1, bhh1, lane);
  else if (wid == 4) load_w1<5 >(wf, Wih1, Whh1, bih1, bhh1, lane);
  else if (wid == 5) load_w1<10>(wf, Wih1, Whh1, bih1, bhh1, lane);
  else if (wid == 6) load_w1<15>(wf, Wih1, Whh1, bih1, bhh1, lane);
  else               load_w1<20>(wf, Wih1, Whh1, bih1, bhh1, lane);

  for (int i = tid; i < 16 * 256; i += 512) hcat[i] = 0;
  __syncthreads();
  if (tid < 16) {
    hset(hcat, tid, 103, 0x3C00u);   // f16 1.0
    hset(hcat, tid, 212, 0x3C00u);
  }
  if (tid < 48) {  // x(t=0)
    int b = tid / 3, i = tid - 3 * (tid / 3);
    hset(hcat, b, 100 + i, f2h(x[(size_t)(b0 + b) * 3072 + i * 1024]));
  }
  __syncthreads();

  float c0[4] = {0.f, 0.f, 0.f, 0.f};
  float c1[4] = {0.f, 0.f, 0.f, 0.f};
  const int uu = tid & 127;     // unit (active if <100)
  const int bq = tid >> 7;      // batch quarter

  for (int e = 0; e <= T_SEQ; ++e) {
    // ---- Phase A: GEMM0 computes step e; GEMM1 computes step e-1 ----
    if (wid < 3) {
      if (e < T_SEQ) {
        if (wid == 0)      gemm0_run<9, 0 >(wf, hcat, gates0, lane);
        else if (wid == 1) gemm0_run<8, 9 >(wf, hcat, gates0, lane);
        else               gemm0_run<8, 17>(wf, hcat, gates0, lane);
      }
    } else if (e >= 1) {
      if (wid == 3)      gemm1_run<0 >(wf, hcat, gates1, lane);
      else if (wid == 4) gemm1_run<5 >(wf, hcat, gates1, lane);
      else if (wid == 5) gemm1_run<10>(wf, hcat, gates1, lane);
      else if (wid == 6) gemm1_run<15>(wf, hcat, gates1, lane);
      else               gemm1_run<20>(wf, hcat, gates1, lane);
    }
    __syncthreads();

    // ---- Phase B: gate nonlinearity + state update (+ x prefetch) ----
    if (uu < 100) {
      #pragma unroll
      for (int bi = 0; bi < 4; ++bi) {
        const int b = (bq << 2) + bi;
        if (e < T_SEQ) {  // layer-0 update for step e
          f32x4 gv = *reinterpret_cast<const f32x4*>(&gates0[(b * 100 + uu) * 4]);
          float i_ = sigmoid_f(gv[0]);
          float f_ = sigmoid_f(gv[1]);
          float g_ = tanh_f(gv[2]);
          float o_ = sigmoid_f(gv[3]);
          c0[bi] = f_ * c0[bi] + i_ * g_;
          float h = o_ * tanh_f(c0[bi]);
          hset(hcat, b, uu, f2h(h));
        }
        if (e >= 1) {     // layer-1 update for step e-1
          f32x4 gv = *reinterpret_cast<const f32x4*>(&gates1[(b * 100 + uu) * 4]);
          float i_ = sigmoid_f(gv[0]);
          float f_ = sigmoid_f(gv[1]);
          float g_ = tanh_f(gv[2]);
          float o_ = sigmoid_f(gv[3]);
          c1[bi] = f_ * c1[bi] + i_ * g_;
          float h = o_ * tanh_f(c1[bi]);
          hset(hcat, b, 112 + uu, f2h(h));
          if (e == T_SEQ) gates0[(b * 100 + uu) * 4] = h;  // f32 staging for FC
        }
      }
    } else {
      // x prefetch for step e+1 (slots 0..47 over waves 1 and 3)
      int slot = bq * 28 + (uu - 100);
      if (slot < 48 && e < T_SEQ - 1) {
        int b = slot / 3, i = slot - 3 * (slot / 3);
        hset(hcat, b, 100 + i, f2h(x[(size_t)(b0 + b) * 3072 + i * 1024 + (e + 1)]));
      }
    }
    __syncthreads();
  }

  // ---- FC: out[b][j] = fc_b[j] + sum_u fc_w[j][u] * h1_final[b][u] ----
  if (tid < 160) {
    int b = tid / 10, j = tid - 10 * (tid / 10);
    float acc = fcb[j];
    for (int u2 = 0; u2 < 100; ++u2)
      acc += fcw[j * 100 + u2] * gates0[(b * 100 + u2) * 4];
    out[(size_t)(b0 + b) * 10 + j] = acc;
  }
}

extern "C" void kernel_launch(void* const* d_in, const int* in_sizes, int n_in,
                              void* d_out, int out_size, void* d_ws, size_t ws_size,
                              hipStream_t stream) {
  (void)in_sizes; (void)n_in; (void)d_ws; (void)ws_size; (void)out_size;
  const float* x    = (const float*)d_in[0];
  const float* Wih0 = (const float*)d_in[1];
  const float* Whh0 = (const float*)d_in[2];
  const float* bih0 = (const float*)d_in[3];
  const float* bhh0 = (const float*)d_in[4];
  const float* Wih1 = (const float*)d_in[5];
  const float* Whh1 = (const float*)d_in[6];
  const float* bih1 = (const float*)d_in[7];
  const float* bhh1 = (const float*)d_in[8];
  const float* fcw  = (const float*)d_in[9];
  const float* fcb  = (const float*)d_in[10];
  hipLaunchKernelGGL(lstm2_kernel, dim3(64), dim3(512), 0, stream,
                     x, Wih0, Whh0, bih0, bhh0, Wih1, Whh1, bih1, bhh1,
                     fcw, fcb, (float*)d_out);
}

// Round 3
// 1388.319 us; speedup vs baseline: 4.5387x; 4.5387x over previous
//
#include <hip/hip_runtime.h>
#include <hip/hip_fp16.h>

// 2-layer LSTM (T=1024, B=1024, H=100) + FC, fused persistent kernel.
// R3: 256 blocks x 4 batch rows (all CUs), fast activations (v_exp/v_rcp),
// conflict-free gate planes [q][b][u].
// Waves 0-2: layer-0 GEMM (MFMA 16x16x32 f16, K=128: h0|x|bias folded).
// Waves 3-7: layer-1 concat GEMM (K=224: W_ih1|pad|W_hh1|bias), lagged one
// step (software pipeline, 2 barriers/epoch). Weights resident in registers.

#define T_SEQ 1024

typedef __attribute__((ext_vector_type(8))) _Float16 half8;
typedef __attribute__((ext_vector_type(4))) float f32x4;

__device__ __forceinline__ unsigned short f2h(float f) {
  _Float16 h = (_Float16)f;
  return *reinterpret_cast<unsigned short*>(&h);
}

// sigma(x) = 1/(1+2^(-x*log2e)); v_exp_f32 + v_rcp_f32, ~1ulp each.
__device__ __forceinline__ float fast_sig(float x) {
  return __builtin_amdgcn_rcpf(1.0f + __builtin_amdgcn_exp2f(-1.4426950408889634f * x));
}
// tanh(x) = 1 - 2/(1+e^(2x))
__device__ __forceinline__ float fast_tanh(float x) {
  return 1.0f - 2.0f * __builtin_amdgcn_rcpf(1.0f + __builtin_amdgcn_exp2f(2.8853900817779268f * x));
}

// Swizzled f16 store into hcat: row b (0..15), slot s (0..255).
// byte = b*512 + ((2s) ^ ((b&7)<<4)) -- matches the b128 A-fragment reads.
__device__ __forceinline__ void hset(unsigned short* hcat, int b, int s, unsigned short v) {
  int byte = b * 512 + ((s * 2) ^ ((b & 7) << 4));
  *reinterpret_cast<unsigned short*>(reinterpret_cast<char*>(hcat) + byte) = v;
}

// ---- weight fragment loaders (init only) ----
template<int NT_, int TB>
__device__ __forceinline__ void load_w0(half8 (&wf)[36], const float* Whh0, const float* Wih0,
                                        const float* bih0, const float* bhh0, int lane) {
  const int r = lane & 15, hi = lane >> 4;
  #pragma unroll
  for (int t = 0; t < NT_; ++t) {
    const int g = (TB + t) * 16 + r;
    #pragma unroll
    for (int ks = 0; ks < 4; ++ks) {
      half8 v;
      #pragma unroll
      for (int j = 0; j < 8; ++j) {
        const int k = ks * 32 + hi * 8 + j;
        float val = 0.f;
        if (k < 100) val = Whh0[g * 100 + k];
        else if (k < 103) val = Wih0[g * 3 + (k - 100)];
        else if (k == 103) val = bih0[g] + bhh0[g];
        v[j] = (_Float16)val;
      }
      wf[t * 4 + ks] = v;
    }
  }
}

template<int TB>
__device__ __forceinline__ void load_w1(half8 (&wf)[36], const float* Wih1, const float* Whh1,
                                        const float* bih1, const float* bhh1, int lane) {
  const int r = lane & 15, hi = lane >> 4;
  #pragma unroll
  for (int t = 0; t < 5; ++t) {
    const int g = (TB + t) * 16 + r;
    #pragma unroll
    for (int ks = 0; ks < 7; ++ks) {
      half8 v;
      #pragma unroll
      for (int j = 0; j < 8; ++j) {
        const int k = ks * 32 + hi * 8 + j;
        float val = 0.f;
        if (k < 100) val = Wih1[g * 100 + k];
        else if (k >= 112 && k < 212) val = Whh1[g * 100 + (k - 112)];
        else if (k == 212) val = bih1[g] + bhh1[g];
        v[j] = (_Float16)val;
      }
      wf[t * 7 + ks] = v;
    }
  }
}

// ---- per-epoch GEMMs ----
// A-frag: lane holds A[r=lane&15][k=(lane>>4)*8+j]; B-frag: B[k][c=lane&15].
// D: col=lane&15 (gate), row=(lane>>4)*4+reg (batch row). Only rows 0-3 are
// live (hi==0 lanes store). Gate planes: gates[q*512 + b*128 + u].
template<int NT_, int TB>
__device__ __forceinline__ void gemm0_run(const half8 (&wf)[36], const unsigned short* hcat,
                                          float* gates, int lane) {
  const int r = lane & 15, hi = lane >> 4;
  const int swz = (r & 7) << 4;
  const char* hb = reinterpret_cast<const char*>(hcat);
  half8 a[4];
  #pragma unroll
  for (int ks = 0; ks < 4; ++ks)
    a[ks] = *reinterpret_cast<const half8*>(hb + r * 512 + ((ks * 64 + hi * 16) ^ swz));
  f32x4 acc[NT_];
  #pragma unroll
  for (int t = 0; t < NT_; ++t) acc[t] = f32x4{0.f, 0.f, 0.f, 0.f};
  #pragma unroll
  for (int ks = 0; ks < 4; ++ks) {
    #pragma unroll
    for (int t = 0; t < NT_; ++t)
      acc[t] = __builtin_amdgcn_mfma_f32_16x16x32_f16(a[ks], wf[t * 4 + ks], acc[t], 0, 0, 0);
  }
  if (hi == 0) {
    #pragma unroll
    for (int t = 0; t < NT_; ++t) {
      const int g = (TB + t) * 16 + r;
      const int q = (g >= 300) ? 3 : (g >= 200) ? 2 : (g >= 100) ? 1 : 0;
      const int u = g - q * 100;
      #pragma unroll
      for (int q2 = 0; q2 < 4; ++q2)
        gates[q * 512 + q2 * 128 + u] = acc[t][q2];
    }
  }
}

template<int TB>
__device__ __forceinline__ void gemm1_run(const half8 (&wf)[36], const unsigned short* hcat,
                                          float* gates, int lane) {
  const int r = lane & 15, hi = lane >> 4;
  const int swz = (r & 7) << 4;
  const char* hb = reinterpret_cast<const char*>(hcat);
  half8 a[7];
  #pragma unroll
  for (int ks = 0; ks < 7; ++ks)
    a[ks] = *reinterpret_cast<const half8*>(hb + r * 512 + ((ks * 64 + hi * 16) ^ swz));
  f32x4 acc[5];
  #pragma unroll
  for (int t = 0; t < 5; ++t) acc[t] = f32x4{0.f, 0.f, 0.f, 0.f};
  #pragma unroll
  for (int ks = 0; ks < 7; ++ks) {
    #pragma unroll
    for (int t = 0; t < 5; ++t)
      acc[t] = __builtin_amdgcn_mfma_f32_16x16x32_f16(a[ks], wf[t * 7 + ks], acc[t], 0, 0, 0);
  }
  if (hi == 0) {
    #pragma unroll
    for (int t = 0; t < 5; ++t) {
      const int g = (TB + t) * 16 + r;
      const int q = (g >= 300) ? 3 : (g >= 200) ? 2 : (g >= 100) ? 1 : 0;
      const int u = g - q * 100;
      #pragma unroll
      for (int q2 = 0; q2 < 4; ++q2)
        gates[q * 512 + q2 * 128 + u] = acc[t][q2];
    }
  }
}

__global__ __launch_bounds__(512, 2)
void lstm2_kernel(const float* __restrict__ x,
                  const float* __restrict__ Wih0, const float* __restrict__ Whh0,
                  const float* __restrict__ bih0, const float* __restrict__ bhh0,
                  const float* __restrict__ Wih1, const float* __restrict__ Whh1,
                  const float* __restrict__ bih1, const float* __restrict__ bhh1,
                  const float* __restrict__ fcw, const float* __restrict__ fcb,
                  float* __restrict__ out) {
  // hcat slots: [0,100)=h0, 100-102=x(t), 103=1.0, [112,212)=h1, 212=1.0.
  // Rows 0-3 live, 4-15 stay zero (MFMA M-padding). Rows swizzled.
  __shared__ unsigned short hcat[16 * 256];   // 8 KB
  __shared__ float gates0[4 * 4 * 128];       // 8 KB, [q][b][u]
  __shared__ float gates1[4 * 4 * 128];       // 8 KB

  const int tid  = threadIdx.x;
  const int lane = tid & 63;
  const int wid  = tid >> 6;
  const int b0   = blockIdx.x << 2;           // 4 batch rows per block

  half8 wf[36];   // role-unioned register weight fragments
  #pragma unroll
  for (int i = 0; i < 36; ++i) wf[i] = half8{0,0,0,0,0,0,0,0};

  if (wid == 0)      load_w0<9, 0 >(wf, Whh0, Wih0, bih0, bhh0, lane);
  else if (wid == 1) load_w0<8, 9 >(wf, Whh0, Wih0, bih0, bhh0, lane);
  else if (wid == 2) load_w0<8, 17>(wf, Whh0, Wih0, bih0, bhh0, lane);
  else if (wid == 3) load_w1<0 >(wf, Wih1, Whh1, bih1, bhh1, lane);
  else if (wid == 4) load_w1<5 >(wf, Wih1, Whh1, bih1, bhh1, lane);
  else if (wid == 5) load_w1<10>(wf, Wih1, Whh1, bih1, bhh1, lane);
  else if (wid == 6) load_w1<15>(wf, Wih1, Whh1, bih1, bhh1, lane);
  else               load_w1<20>(wf, Wih1, Whh1, bih1, bhh1, lane);

  for (int i = tid; i < 16 * 256; i += 512) hcat[i] = 0;
  __syncthreads();
  if (tid < 16) {
    hset(hcat, tid, 103, 0x3C00u);   // f16 1.0 (bias slot, GEMM0)
    hset(hcat, tid, 212, 0x3C00u);   // f16 1.0 (bias slot, GEMM1)
  }
  if (tid < 12) {  // x(t=0) for 4 rows x 3 channels
    int b = tid / 3, i = tid - 3 * (tid / 3);
    hset(hcat, b, 100 + i, f2h(x[(size_t)(b0 + b) * 3072 + i * 1024]));
  }
  __syncthreads();

  float c0 = 0.f, c1 = 0.f;
  const int uu = tid & 127;     // unit (active if <100)
  const int bb = tid >> 7;      // batch row 0..3

  for (int e = 0; e <= T_SEQ; ++e) {
    // ---- Phase A: GEMM0 computes step e; GEMM1 computes step e-1 ----
    if (wid < 3) {
      if (e < T_SEQ) {
        if (wid == 0)      gemm0_run<9, 0 >(wf, hcat, gates0, lane);
        else if (wid == 1) gemm0_run<8, 9 >(wf, hcat, gates0, lane);
        else               gemm0_run<8, 17>(wf, hcat, gates0, lane);
      }
    } else if (e >= 1) {
      if (wid == 3)      gemm1_run<0 >(wf, hcat, gates1, lane);
      else if (wid == 4) gemm1_run<5 >(wf, hcat, gates1, lane);
      else if (wid == 5) gemm1_run<10>(wf, hcat, gates1, lane);
      else if (wid == 6) gemm1_run<15>(wf, hcat, gates1, lane);
      else               gemm1_run<20>(wf, hcat, gates1, lane);
    }
    __syncthreads();

    // ---- Phase B: gate nonlinearity + state update (1 unit/thread/layer) ----
    if (uu < 100) {
      const int o4 = bb * 128 + uu;
      if (e < T_SEQ) {  // layer-0 update for step e
        float i_ = fast_sig (gates0[          o4]);
        float f_ = fast_sig (gates0[1 * 512 + o4]);
        float g_ = fast_tanh(gates0[2 * 512 + o4]);
        float o_ = fast_sig (gates0[3 * 512 + o4]);
        c0 = f_ * c0 + i_ * g_;
        hset(hcat, bb, uu, f2h(o_ * fast_tanh(c0)));
      }
      if (e >= 1) {     // layer-1 update for step e-1
        float i_ = fast_sig (gates1[          o4]);
        float f_ = fast_sig (gates1[1 * 512 + o4]);
        float g_ = fast_tanh(gates1[2 * 512 + o4]);
        float o_ = fast_sig (gates1[3 * 512 + o4]);
        c1 = f_ * c1 + i_ * g_;
        float h = o_ * fast_tanh(c1);
        hset(hcat, bb, 112 + uu, f2h(h));
        if (e == T_SEQ) gates0[o4] = h;   // f32 staging for FC
      }
    } else if (uu < 103 && e + 1 < T_SEQ) {
      // x prefetch for step e+1 (3 channels x 4 rows = 12 threads)
      int i = uu - 100;
      hset(hcat, bb, 100 + i, f2h(x[(size_t)(b0 + bb) * 3072 + i * 1024 + (e + 1)]));
    }
    __syncthreads();
  }

  // ---- FC: out[b][j] = fc_b[j] + sum_u fc_w[j][u] * h1_final[b][u] ----
  if (tid < 40) {
    int b = tid / 10, j = tid - 10 * (tid / 10);
    float acc = fcb[j];
    for (int u2 = 0; u2 < 100; ++u2)
      acc += fcw[j * 100 + u2] * gates0[b * 128 + u2];
    out[(size_t)(b0 + b) * 10 + j] = acc;
  }
}

extern "C" void kernel_launch(void* const* d_in, const int* in_sizes, int n_in,
                              void* d_out, int out_size, void* d_ws, size_t ws_size,
                              hipStream_t stream) {
  (void)in_sizes; (void)n_in; (void)d_ws; (void)ws_size; (void)out_size;
  const float* x    = (const float*)d_in[0];
  const float* Wih0 = (const float*)d_in[1];
  const float* Whh0 = (const float*)d_in[2];
  const float* bih0 = (const float*)d_in[3];
  const float* bhh0 = (const float*)d_in[4];
  const float* Wih1 = (const float*)d_in[5];
  const float* Whh1 = (const float*)d_in[6];
  const float* bih1 = (const float*)d_in[7];
  const float* bhh1 = (const float*)d_in[8];
  const float* fcw  = (const float*)d_in[9];
  const float* fcb  = (const float*)d_in[10];
  hipLaunchKernelGGL(lstm2_kernel, dim3(256), dim3(512), 0, stream,
                     x, Wih0, Whh0, bih0, bhh0, Wih1, Whh1, bih1, bhh1,
                     fcw, fcb, (float*)d_out);
}